// Round 3
// baseline (286.236 us; speedup 1.0000x reference)
//
#include <hip/hip_runtime.h>
#include <hip/hip_bf16.h>
#include <math.h>

// ---------------------------------------------------------------------------
// WaveletEmbedding: 4-level db4 2D DWT (symmetric) -> detail magnitudes ->
// bilinear upsample -> sigmoid gating.  B=16, C=2, H=W=512, N_SCALES=4.
// Level sizes: 512 -> 259 -> 133 -> 70 -> 38   (n_out = (N+7)>>1)
// All I/O f32.  Round 3: fused row+col DWT per level (LDS), gate folded
// into final kernel.  5 dispatches total.
// ---------------------------------------------------------------------------

#define EPSV 1e-8f

__constant__ float c_lo[8] = {
    -0.010597401784997278f,  0.032883011666982945f,  0.030841381835986965f,
    -0.18703481171888114f,  -0.02798376941698385f,   0.6308807679295904f,
     0.7148465705525415f,    0.23037781330885523f };
// DEC_HI[i] = DEC_LO[7-i] * (i even ? -1 : +1)
__constant__ float c_hi[8] = {
    -0.23037781330885523f,   0.7148465705525415f,   -0.6308807679295904f,
    -0.02798376941698385f,   0.18703481171888114f,   0.030841381835986965f,
    -0.032883011666982945f, -0.010597401784997278f };

__device__ __forceinline__ int symi(int i, int n) {
    // half-sample symmetric extension, single reflection (valid: |overhang|<n)
    i = (i < 0) ? (-1 - i) : i;
    i = (i >= n) ? (2 * n - 1 - i) : i;
    return i;
}

// ---------------- fused per-level DWT: in[N x N] -> cA,mag [M x M] ---------
// One block computes a TO x TO output tile for one image.
// Row-DWT results are staged in LDS ([2*TO+6][TO+1], padded), col-DWT reads
// them back.  Row stride 33 floats -> half-wave bank aliasing is 2-way (free).
template <int TO>
__global__ __launch_bounds__(256)
void dwt_level(const float* __restrict__ in, float* __restrict__ cA,
               float* __restrict__ mag, int N, int M, int tilesX) {
    constexpr int R = 2 * TO + 6;
    __shared__ float s_lo[R][TO + 1];
    __shared__ float s_hi[R][TO + 1];

    int T  = tilesX * tilesX;
    int n  = blockIdx.x / T;
    int t  = blockIdx.x % T;
    int tx = t % tilesX, ty = t / tilesX;
    int ox0 = tx * TO, oy0 = ty * TO;
    const float* img = in + (size_t)n * N * N;
    int qbase = 2 * oy0 - 6;

    // stage 1: row DWT for all R input rows needed by this output tile
    for (int e = threadIdx.x; e < R * TO; e += 256) {
        int r = e / TO, k = e % TO;
        int gq = symi(qbase + r, N);
        const float* row = img + (size_t)gq * N;
        int base = 2 * (ox0 + k) + 1;
        float lo = 0.f, hi = 0.f;
#pragma unroll
        for (int j = 0; j < 8; ++j) {
            float x = row[symi(base - j, N)];
            lo += c_lo[j] * x;
            hi += c_hi[j] * x;
        }
        s_lo[r][k] = lo;
        s_hi[r][k] = hi;
    }
    __syncthreads();

    // stage 2: column DWT from LDS -> cA (=LL) and magnitude(LH,HL,HH)
    for (int e = threadIdx.x; e < TO * TO; e += 256) {
        int ly = e / TO, k = e % TO;
        int oy = oy0 + ly, ox = ox0 + k;
        if (oy >= M || ox >= M) continue;
        float ll = 0.f, lh = 0.f, hl = 0.f, hh = 0.f;
#pragma unroll
        for (int j = 0; j < 8; ++j) {
            int r = 2 * ly + 7 - j;
            float a = s_lo[r][k];
            float b = s_hi[r][k];
            ll += c_lo[j] * a;
            lh += c_hi[j] * a;
            hl += c_lo[j] * b;
            hh += c_hi[j] * b;
        }
        size_t o = (size_t)n * M * M + (size_t)oy * M + ox;
        cA[o]  = ll;
        mag[o] = sqrtf(lh * lh + hl * hl + hh * hh + EPSV);
    }
}

// ------------------- bilinear upsample (half-pixel, edge clamp) ------------
__device__ __forceinline__ float bilerp(const float* __restrict__ src, int n,
                                        int i, int j) {
    float scale = (float)n * (1.0f / 512.0f);
    float ui = ((float)i + 0.5f) * scale - 0.5f;
    float uj = ((float)j + 0.5f) * scale - 0.5f;
    float fi0 = floorf(ui), fj0 = floorf(uj);
    float fi = ui - fi0, fj = uj - fj0;
    int i0 = (int)fi0, j0 = (int)fj0;
    int i0c = min(max(i0, 0), n - 1);
    int i1c = min(max(i0 + 1, 0), n - 1);
    int j0c = min(max(j0, 0), n - 1);
    int j1c = min(max(j0 + 1, 0), n - 1);
    const float* r0 = src + (size_t)i0c * n;
    const float* r1 = src + (size_t)i1c * n;
    float v00 = r0[j0c], v01 = r0[j1c];
    float v10 = r1[j0c], v11 = r1[j1c];
    float t0 = v00 + (v01 - v00) * fj;
    float t1 = v10 + (v11 - v10) * fj;
    return t0 + (t1 - t0) * fi;
}

// ------------- final: gate(matvec+sigmoid) + upsample + f32 store ----------
// Blocks are 256-aligned in the flat index -> (b, s, i) are block-uniform;
// wave 0 computes the single gate weight this block needs.
__global__ __launch_bounds__(256)
void final_kernel(const float* __restrict__ cA4, const float* __restrict__ mag4,
                  const float* __restrict__ mag3, const float* __restrict__ mag2,
                  const float* __restrict__ mag1,
                  const float* __restrict__ t_emb, const float* __restrict__ gate_w,
                  float* __restrict__ out) {
    __shared__ float s_sw;
    int idx = blockIdx.x * 256 + threadIdx.x;
    int j  = idx & 511;
    int i  = (idx >> 9) & 511;
    int ch = (idx >> 18) & 7;
    int b  = idx >> 21;
    int s  = ch & 3;
    int c  = ch >> 2;
    int n  = b * 2 + c;

    if (threadIdx.x < 64) {
        float v = t_emb[b * 64 + threadIdx.x] * gate_w[threadIdx.x * 4 + s];
#pragma unroll
        for (int off = 32; off > 0; off >>= 1) v += __shfl_down(v, off);
        if (threadIdx.x == 0) s_sw = 1.f / (1.f + expf(-v));
    }
    __syncthreads();

    float val;
    if (s == 0) {
        const float* a = cA4  + (size_t)n * 38 * 38;
        const float* m = mag4 + (size_t)n * 38 * 38;
        val = 0.5f * (bilerp(a, 38, i, j) + bilerp(m, 38, i, j));
    } else if (s == 1) {
        val = bilerp(mag3 + (size_t)n * 70 * 70, 70, i, j);
    } else if (s == 2) {
        val = bilerp(mag2 + (size_t)n * 133 * 133, 133, i, j);
    } else {
        val = bilerp(mag1 + (size_t)n * 259 * 259, 259, i, j);
    }
    out[idx] = val * s_sw;
}

// ---------------------------------------------------------------------------
extern "C" void kernel_launch(void* const* d_in, const int* in_sizes, int n_in,
                              void* d_out, int out_size, void* d_ws, size_t ws_size,
                              hipStream_t stream) {
    (void)in_sizes; (void)n_in; (void)out_size; (void)ws_size;
    const float* image  = (const float*)d_in[0];
    const float* t_emb  = (const float*)d_in[1];
    const float* gate_w = (const float*)d_in[2];
    float* out = (float*)d_out;
    float* ws = (float*)d_ws;

    const int NI = 32;                       // B*C images
    const int S1 = 259 * 259, S2 = 133 * 133, S3 = 70 * 70, S4 = 38 * 38;

    // workspace layout (floats), ~28 MB
    size_t off = 0;
    float* mag1 = ws + off; off += (size_t)NI * S1;
    float* mag2 = ws + off; off += (size_t)NI * S2;
    float* mag3 = ws + off; off += (size_t)NI * S3;
    float* mag4 = ws + off; off += (size_t)NI * S4;
    float* cA1  = ws + off; off += (size_t)NI * S1;
    float* cA2  = ws + off; off += (size_t)NI * S2;
    float* cA3  = ws + off; off += (size_t)NI * S3;
    float* cA4  = ws + off; off += (size_t)NI * S4;

    const int TO = 32;
    auto tiles = [](int M) { return (M + TO - 1) / TO; };

    // level 1: 512 -> 259
    { int tX = tiles(259);
      dwt_level<TO><<<NI * tX * tX, 256, 0, stream>>>(image, cA1, mag1, 512, 259, tX); }
    // level 2: 259 -> 133
    { int tX = tiles(133);
      dwt_level<TO><<<NI * tX * tX, 256, 0, stream>>>(cA1, cA2, mag2, 259, 133, tX); }
    // level 3: 133 -> 70
    { int tX = tiles(70);
      dwt_level<TO><<<NI * tX * tX, 256, 0, stream>>>(cA2, cA3, mag3, 133, 70, tX); }
    // level 4: 70 -> 38
    { int tX = tiles(38);
      dwt_level<TO><<<NI * tX * tX, 256, 0, stream>>>(cA3, cA4, mag4, 70, 38, tX); }

    // final: gate + upsample + store (16*8*512*512 threads)
    { int total = 16 * 8 * 512 * 512;
      final_kernel<<<total / 256, 256, 0, stream>>>(cA4, mag4, mag3, mag2, mag1,
                                                    t_emb, gate_w, out); }
}

// Round 4
// 214.525 us; speedup vs baseline: 1.3343x; 1.3343x over previous
//
#include <hip/hip_runtime.h>
#include <hip/hip_bf16.h>
#include <math.h>

// ---------------------------------------------------------------------------
// WaveletEmbedding: 4-level db4 2D DWT (symmetric) -> detail magnitudes ->
// bilinear upsample -> sigmoid gating.  B=16, C=2, H=W=512, N_SCALES=4.
// Level sizes: 512 -> 259 -> 133 -> 70 -> 38.  All I/O f32.
// Round 4: LDS-tiled final (patch-cached bilerp, float4 stores), level-4
// pre-averages (cA4+mag4)/2 (resize is linear), dwt interior fast path.
// ---------------------------------------------------------------------------

#define EPSV 1e-8f

__constant__ float c_lo[8] = {
    -0.010597401784997278f,  0.032883011666982945f,  0.030841381835986965f,
    -0.18703481171888114f,  -0.02798376941698385f,   0.6308807679295904f,
     0.7148465705525415f,    0.23037781330885523f };
// DEC_HI[i] = DEC_LO[7-i] * (i even ? -1 : +1)
__constant__ float c_hi[8] = {
    -0.23037781330885523f,   0.7148465705525415f,   -0.6308807679295904f,
    -0.02798376941698385f,   0.18703481171888114f,   0.030841381835986965f,
    -0.032883011666982945f, -0.010597401784997278f };

__device__ __forceinline__ int symi(int i, int n) {
    i = (i < 0) ? (-1 - i) : i;
    i = (i >= n) ? (2 * n - 1 - i) : i;
    return i;
}

// ---------------- fused per-level DWT: in[N x N] -> cA,mag [M x M] ---------
// AVG=true (level 4): mag <- 0.5*(LL + |detail|), no cA output.
template <int TO, bool AVG>
__global__ __launch_bounds__(256)
void dwt_level(const float* __restrict__ in, float* __restrict__ cA,
               float* __restrict__ mag, int N, int M, int tilesX) {
    constexpr int R = 2 * TO + 6;
    __shared__ float s_lo[R][TO + 1];
    __shared__ float s_hi[R][TO + 1];

    int T  = tilesX * tilesX;
    int n  = blockIdx.x / T;
    int t  = blockIdx.x % T;
    int tx = t % tilesX, ty = t / tilesX;
    int ox0 = tx * TO, oy0 = ty * TO;
    const float* img = in + (size_t)n * N * N;
    int qbase = 2 * oy0 - 6;

    // stage 1: row DWT for all R input rows needed by this tile
    for (int e = threadIdx.x; e < R * TO; e += 256) {
        int r = e / TO, k = e % TO;
        int gq = symi(qbase + r, N);
        const float* row = img + (size_t)gq * N;
        int base = 2 * (ox0 + k) + 1;
        float lo = 0.f, hi = 0.f;
        if (base >= 7 && base < N) {            // all taps interior
            const float* p = row + base - 7;    // x[m] = row[base-7+m]
#pragma unroll
            for (int j = 0; j < 8; ++j) {
                float x = p[7 - j];
                lo += c_lo[j] * x;
                hi += c_hi[j] * x;
            }
        } else {
#pragma unroll
            for (int j = 0; j < 8; ++j) {
                float x = row[symi(base - j, N)];
                lo += c_lo[j] * x;
                hi += c_hi[j] * x;
            }
        }
        s_lo[r][k] = lo;
        s_hi[r][k] = hi;
    }
    __syncthreads();

    // stage 2: column DWT from LDS -> outputs
    for (int e = threadIdx.x; e < TO * TO; e += 256) {
        int ly = e / TO, k = e % TO;
        int oy = oy0 + ly, ox = ox0 + k;
        if (oy >= M || ox >= M) continue;
        float ll = 0.f, lh = 0.f, hl = 0.f, hh = 0.f;
#pragma unroll
        for (int j = 0; j < 8; ++j) {
            int r = 2 * ly + 7 - j;
            float a = s_lo[r][k];
            float b = s_hi[r][k];
            ll += c_lo[j] * a;
            lh += c_hi[j] * a;
            hl += c_lo[j] * b;
            hh += c_hi[j] * b;
        }
        size_t o = (size_t)n * M * M + (size_t)oy * M + ox;
        float m = sqrtf(lh * lh + hl * hl + hh * hh + EPSV);
        if (AVG) {
            mag[o] = 0.5f * (ll + m);
        } else {
            cA[o]  = ll;
            mag[o] = m;
        }
    }
}

// ------------- final: gate + LDS-patch bilinear upsample + store -----------
// Block = 64x64 output tile of one (image n, scale s).  8 tiles/dim.
// Source patch (<=34x34 floats) staged in LDS; all bilerp taps hit LDS.
#define PMAX 34
#define PSTR 35
__global__ __launch_bounds__(256)
void final_kernel(const float* __restrict__ f0,   const float* __restrict__ mag3,
                  const float* __restrict__ mag2, const float* __restrict__ mag1,
                  const float* __restrict__ t_emb, const float* __restrict__ gate_w,
                  float* __restrict__ out) {
    __shared__ float patch[PMAX * PSTR];
    __shared__ float s_sw;

    int blk  = blockIdx.x;
    int tile = blk & 63;          // 8x8 tiles
    int s    = (blk >> 6) & 3;
    int n    = blk >> 8;          // image 0..31
    int b    = n >> 1, c = n & 1;
    int ti0  = (tile >> 3) * 64, tj0 = (tile & 7) * 64;

    const float* src; int ns;
    if      (s == 0) { src = f0;   ns = 38;  }
    else if (s == 1) { src = mag3; ns = 70;  }
    else if (s == 2) { src = mag2; ns = 133; }
    else             { src = mag1; ns = 259; }
    src += (size_t)n * ns * ns;
    float sc = (float)ns * (1.0f / 512.0f);

    // gate weight (block-uniform): first wave reduces the 64-dot
    if (threadIdx.x < 64) {
        float v = t_emb[b * 64 + threadIdx.x] * gate_w[threadIdx.x * 4 + s];
#pragma unroll
        for (int off = 32; off > 0; off >>= 1) v += __shfl_down(v, off);
        if (threadIdx.x == 0) s_sw = 1.f / (1.f + expf(-v));
    }

    // source patch bounds covering output rows [ti0, ti0+63], cols [tj0, tj0+63]
    int pr0 = max(0, (int)floorf(((float)ti0 + 0.5f) * sc - 0.5f));
    int pr1 = min(ns - 1, (int)floorf(((float)ti0 + 63.5f) * sc - 0.5f) + 1);
    int pc0 = max(0, (int)floorf(((float)tj0 + 0.5f) * sc - 0.5f));
    int pc1 = min(ns - 1, (int)floorf(((float)tj0 + 63.5f) * sc - 0.5f) + 1);
    int rows = pr1 - pr0 + 1, cols = pc1 - pc0 + 1;

    for (int e = threadIdx.x; e < rows * cols; e += 256) {
        int r = e / cols, cc = e % cols;
        patch[r * PSTR + cc] = src[(size_t)(pr0 + r) * ns + (pc0 + cc)];
    }
    __syncthreads();

    // thread -> 4 cols (tx*4..tx*4+3) x 4 rows (ty, ty+16, ty+32, ty+48)
    int tx = threadIdx.x & 15, ty = threadIdx.x >> 4;
    float sw = s_sw;

    // column weights, computed once, reused for all 4 rows
    int   j0r[4], j1r[4];
    float fjr[4];
#pragma unroll
    for (int q = 0; q < 4; ++q) {
        int j = tj0 + tx * 4 + q;
        float uj = ((float)j + 0.5f) * sc - 0.5f;
        float f0j = floorf(uj);
        int j0 = (int)f0j;
        fjr[q] = uj - f0j;
        j0r[q] = min(max(j0, 0), ns - 1) - pc0;
        j1r[q] = min(max(j0 + 1, 0), ns - 1) - pc0;
    }

    size_t obase = (((size_t)b * 8 + (c * 4 + s)) * 512) * 512;
#pragma unroll
    for (int rr = 0; rr < 4; ++rr) {
        int i = ti0 + ty + rr * 16;
        float ui = ((float)i + 0.5f) * sc - 0.5f;
        float f0i = floorf(ui);
        int i0 = (int)f0i;
        float fi = ui - f0i;
        const float* r0 = patch + (min(max(i0, 0), ns - 1) - pr0) * PSTR;
        const float* r1 = patch + (min(max(i0 + 1, 0), ns - 1) - pr0) * PSTR;
        float4 o;
        float* op = (float*)&o;
#pragma unroll
        for (int q = 0; q < 4; ++q) {
            float v00 = r0[j0r[q]], v01 = r0[j1r[q]];
            float v10 = r1[j0r[q]], v11 = r1[j1r[q]];
            float t0 = v00 + (v01 - v00) * fjr[q];
            float t1 = v10 + (v11 - v10) * fjr[q];
            op[q] = (t0 + (t1 - t0) * fi) * sw;
        }
        *(float4*)(out + obase + (size_t)i * 512 + tj0 + tx * 4) = o;
    }
}

// ---------------------------------------------------------------------------
extern "C" void kernel_launch(void* const* d_in, const int* in_sizes, int n_in,
                              void* d_out, int out_size, void* d_ws, size_t ws_size,
                              hipStream_t stream) {
    (void)in_sizes; (void)n_in; (void)out_size; (void)ws_size;
    const float* image  = (const float*)d_in[0];
    const float* t_emb  = (const float*)d_in[1];
    const float* gate_w = (const float*)d_in[2];
    float* out = (float*)d_out;
    float* ws = (float*)d_ws;

    const int NI = 32;
    const int S1 = 259 * 259, S2 = 133 * 133, S3 = 70 * 70, S4 = 38 * 38;

    size_t off = 0;
    float* mag1 = ws + off; off += (size_t)NI * S1;
    float* mag2 = ws + off; off += (size_t)NI * S2;
    float* mag3 = ws + off; off += (size_t)NI * S3;
    float* f0   = ws + off; off += (size_t)NI * S4;   // 0.5*(cA4+mag4)
    float* cA1  = ws + off; off += (size_t)NI * S1;
    float* cA2  = ws + off; off += (size_t)NI * S2;
    float* cA3  = ws + off; off += (size_t)NI * S3;

    const int TO = 32;
    auto tiles = [](int M) { return (M + TO - 1) / TO; };

    { int tX = tiles(259);
      dwt_level<TO, false><<<NI * tX * tX, 256, 0, stream>>>(image, cA1, mag1, 512, 259, tX); }
    { int tX = tiles(133);
      dwt_level<TO, false><<<NI * tX * tX, 256, 0, stream>>>(cA1, cA2, mag2, 259, 133, tX); }
    { int tX = tiles(70);
      dwt_level<TO, false><<<NI * tX * tX, 256, 0, stream>>>(cA2, cA3, mag3, 133, 70, tX); }
    { int tX = tiles(38);
      dwt_level<TO, true><<<NI * tX * tX, 256, 0, stream>>>(cA3, nullptr, f0, 70, 38, tX); }

    // final: 32 images x 4 scales x 64 tiles of 64x64
    final_kernel<<<32 * 4 * 64, 256, 0, stream>>>(f0, mag3, mag2, mag1,
                                                  t_emb, gate_w, out);
}